// Round 10
// baseline (192.535 us; speedup 1.0000x reference)
//
#include <hip/hip_runtime.h>
#include <hip/hip_fp16.h>
#include <math.h>

#define DIM   64
#define SPAN  128           // nodes per bucket
#define SHIFT 7             // log2(SPAN)
#define NBIN  256           // binning blocks
#define KMAX  1024          // max buckets (N <= 131072)
#define CAP   3072          // per-bucket LDS staging (24 KB srec)

// ---------------- Kernel 1: per-node scores + fp16 x copy ------------------
__global__ void score_kernel(const float* __restrict__ x,
                             const float* __restrict__ w_src,
                             const float* __restrict__ w_dst,
                             float* __restrict__ a_src,
                             float* __restrict__ a_dst,
                             __half* __restrict__ xh,
                             int N) {
    int gid  = blockIdx.x * blockDim.x + threadIdx.x;
    int node = gid >> 6;
    int lane = threadIdx.x & 63;
    if (node >= N) return;
    float xv = x[(size_t)node * DIM + lane];
    xh[(size_t)node * DIM + lane] = __float2half_rn(xv);
    float s1 = xv * w_src[lane];
    float s2 = xv * w_dst[lane];
    #pragma unroll
    for (int off = 32; off > 0; off >>= 1) {
        s1 += __shfl_down(s1, off, 64);
        s2 += __shfl_down(s2, off, 64);
    }
    if (lane == 0) {
        a_src[node] = s1;
        a_dst[node] = s2;
    }
}

// ---------------- Kernel 2: coarse histogram matrix ------------------------
// cnt[bucket * NBIN + block] = #edges of bucket seen by block. Deterministic.
__global__ __launch_bounds__(1024) void hist_coarse(
        const int* __restrict__ dst, int* __restrict__ cnt,
        int E, int N, int K) {
    __shared__ int lh[KMAX];
    int tid = threadIdx.x;
    for (int j = tid; j < K; j += blockDim.x) lh[j] = 0;
    __syncthreads();
    for (int base = blockIdx.x * 1024; base < E; base += NBIN * 1024) {
        int e = base + tid;
        if (e < E) {
            unsigned t = (unsigned)dst[e];
            if (t >= (unsigned)N) t = 0;          // guard
            atomicAdd(&lh[t >> SHIFT], 1);
        }
    }
    __syncthreads();
    for (int j = tid; j < K; j += blockDim.x)
        cnt[j * NBIN + blockIdx.x] = lh[j];
}

// ---------------- Kernels 3-4: exclusive scan, 512-wide --------------------
// In-place safe: stages into LDS before any write; block i writes own window.
__global__ __launch_bounds__(512) void scan_part(int* __restrict__ data,
                                                 int* __restrict__ bsum, int n) {
    __shared__ int buf[2][512];
    int tid = threadIdx.x;
    int i = blockIdx.x * 512 + tid;
    int v = (i < n) ? data[i] : 0;
    int sel = 0;
    buf[0][tid] = v;
    __syncthreads();
    for (int off = 1; off < 512; off <<= 1) {
        int nsel = sel ^ 1;
        buf[nsel][tid] = buf[sel][tid] + ((tid >= off) ? buf[sel][tid - off] : 0);
        __syncthreads();
        sel = nsel;
    }
    if (i < n) data[i] = buf[sel][tid] - v;       // exclusive
    if (tid == 511) bsum[blockIdx.x] = buf[sel][511];
}

__global__ __launch_bounds__(512) void scan_top(int* __restrict__ bsum, int NB) {
    __shared__ int buf[2][512];
    int tid = threadIdx.x;
    int v = (tid < NB) ? bsum[tid] : 0;
    int sel = 0;
    buf[0][tid] = v;
    __syncthreads();
    for (int off = 1; off < 512; off <<= 1) {
        int nsel = sel ^ 1;
        buf[nsel][tid] = buf[sel][tid] + ((tid >= off) ? buf[sel][tid - off] : 0);
        __syncthreads();
        sel = nsel;
    }
    if (tid < NB) bsum[tid] = buf[sel][tid] - v;  // exclusive
}

// ---------------- Kernel 5: binpass — pure streaming partition -------------
// No random loads, no tanh. pay = ((src<<8)|dst_local)<<32 | f32bits(ew).
__global__ __launch_bounds__(1024) void binpass_kernel(
        const float* __restrict__ ew,
        const int* __restrict__ src_idx,
        const int* __restrict__ dst_idx,
        const int* __restrict__ moffs,
        const int* __restrict__ bsum,
        unsigned long long* __restrict__ pay,
        int E, int N, int K) {
    __shared__ int lcur[KMAX];
    int tid = threadIdx.x;
    for (int j = tid; j < K; j += blockDim.x) {
        int i = j * NBIN + blockIdx.x;
        lcur[j] = moffs[i] + bsum[i >> 9];        // scan blocks are 512-wide
    }
    __syncthreads();
    for (int base = blockIdx.x * 1024; base < E; base += NBIN * 1024) {
        int e = base + tid;
        if (e < E) {
            unsigned s = (unsigned)src_idx[e];
            unsigned t = (unsigned)dst_idx[e];
            if (s >= (unsigned)N) s = 0;          // guard
            if (t >= (unsigned)N) t = 0;          // guard
            int bk = (int)(t >> SHIFT);
            int pos = atomicAdd(&lcur[bk], 1);    // LDS cursor, block-local
            unsigned rec = (s << 8) | (t & (SPAN - 1));
            pay[pos] = ((unsigned long long)rec << 32) |
                       (unsigned long long)__float_as_uint(ew[e]);
        }
    }
}

// ---------------- Kernel 6: fused sort + attention + gather ----------------
// Stage bucket in LDS, counting-sort index array, then per node:
// lane-parallel a_j = tanh(a_src[s_j]+a_dst[node])*ew_j, shuffle-broadcast
// into 8-deep-unrolled xh row gather. Predicated batches (a=0 for j>=deg).
__global__ __launch_bounds__(1024) void sort_gather_kernel(
        const __half* __restrict__ xh,
        const float* __restrict__ x32,
        const float* __restrict__ a_src,
        const float* __restrict__ a_dst,
        const unsigned long long* __restrict__ pay,
        const int* __restrict__ moffs,
        const int* __restrict__ bsum,
        float* __restrict__ h,
        int N, int K, int E) {
    __shared__ unsigned long long srec[CAP];      // 24 KB
    __shared__ unsigned short sidx[CAP];          // 6 KB
    __shared__ int hcnt[SPAN];
    __shared__ int hoff[2][SPAN];
    __shared__ int lcur[SPAN];
    __shared__ int nstart[SPAN];
    int tid = threadIdx.x;
    int b   = blockIdx.x;
    int i0 = b * NBIN;
    int bstart = moffs[i0] + bsum[i0 >> 9];
    int bend;
    if (b == K - 1) bend = E;
    else { int i1 = (b + 1) * NBIN; bend = moffs[i1] + bsum[i1 >> 9]; }
    int cnt = bend - bstart;

    if (cnt <= CAP) {
        // ---- stage + histogram ----
        if (tid < SPAN) hcnt[tid] = 0;
        __syncthreads();
        for (int i = tid; i < cnt; i += 1024) {
            unsigned long long r = pay[bstart + i];
            srec[i] = r;
            atomicAdd(&hcnt[(int)((r >> 32) & (SPAN - 1))], 1);
        }
        __syncthreads();
        // ---- inclusive scan of hcnt[SPAN] ----
        int sel = 0;
        if (tid < SPAN) hoff[0][tid] = hcnt[tid];
        __syncthreads();
        for (int off = 1; off < SPAN; off <<= 1) {
            int nsel = sel ^ 1;
            if (tid < SPAN)
                hoff[nsel][tid] = hoff[sel][tid] +
                                  ((tid >= off) ? hoff[sel][tid - off] : 0);
            __syncthreads();
            sel = nsel;
        }
        if (tid < SPAN) {
            int excl = hoff[sel][tid] - hcnt[tid];
            nstart[tid] = excl;
            lcur[tid]   = excl;
        }
        __syncthreads();
        // ---- permute indices only ----
        for (int i = tid; i < cnt; i += 1024) {
            unsigned long long r = srec[i];
            int d = (int)((r >> 32) & (SPAN - 1));
            int pos = atomicAdd(&lcur[d], 1);
            sidx[pos] = (unsigned short)i;
        }
        __syncthreads();
        // ---- gather: wave per node ----
        int lane = tid & 63;
        int wave = tid >> 6;                      // 16 waves, 8 nodes each
        for (int d = wave; d < SPAN; d += 16) {
            int node = b * SPAN + d;
            if (node >= N) break;                 // only last bucket
            int p   = nstart[d];
            int deg = hcnt[d];
            float adt = a_dst[node];              // wave-uniform
            float acc0 = 0.f, acc1 = 0.f, acc2 = 0.f, acc3 = 0.f;
            for (int c0 = 0; c0 < deg; c0 += 64) {
                int m = deg - c0; if (m > 64) m = 64;
                float aL = 0.f; unsigned sL = 0;  // lanes >= m contribute 0
                if (lane < m) {
                    unsigned long long r = srec[sidx[p + c0 + lane]];
                    unsigned s = (unsigned)(r >> 40);
                    if (s >= (unsigned)N) s = 0;
                    aL = tanhf(a_src[s] + adt) * __uint_as_float((unsigned)r);
                    sL = s;
                }
                for (int j = 0; j < m; j += 8) {  // predicated full batches
                    unsigned s0 = (unsigned)__shfl((int)sL, j + 0, 64);
                    unsigned s1 = (unsigned)__shfl((int)sL, j + 1, 64);
                    unsigned s2 = (unsigned)__shfl((int)sL, j + 2, 64);
                    unsigned s3 = (unsigned)__shfl((int)sL, j + 3, 64);
                    unsigned s4 = (unsigned)__shfl((int)sL, j + 4, 64);
                    unsigned s5 = (unsigned)__shfl((int)sL, j + 5, 64);
                    unsigned s6 = (unsigned)__shfl((int)sL, j + 6, 64);
                    unsigned s7 = (unsigned)__shfl((int)sL, j + 7, 64);
                    float b0 = __shfl(aL, j + 0, 64);
                    float b1 = __shfl(aL, j + 1, 64);
                    float b2 = __shfl(aL, j + 2, 64);
                    float b3 = __shfl(aL, j + 3, 64);
                    float b4 = __shfl(aL, j + 4, 64);
                    float b5 = __shfl(aL, j + 5, 64);
                    float b6 = __shfl(aL, j + 6, 64);
                    float b7 = __shfl(aL, j + 7, 64);
                    float x0 = __half2float(xh[(size_t)s0 * DIM + lane]);
                    float x1 = __half2float(xh[(size_t)s1 * DIM + lane]);
                    float x2 = __half2float(xh[(size_t)s2 * DIM + lane]);
                    float x3 = __half2float(xh[(size_t)s3 * DIM + lane]);
                    float x4 = __half2float(xh[(size_t)s4 * DIM + lane]);
                    float x5 = __half2float(xh[(size_t)s5 * DIM + lane]);
                    float x6 = __half2float(xh[(size_t)s6 * DIM + lane]);
                    float x7 = __half2float(xh[(size_t)s7 * DIM + lane]);
                    acc0 = fmaf(b0, x0, acc0);
                    acc1 = fmaf(b1, x1, acc1);
                    acc2 = fmaf(b2, x2, acc2);
                    acc3 = fmaf(b3, x3, acc3);
                    acc0 = fmaf(b4, x4, acc0);
                    acc1 = fmaf(b5, x5, acc1);
                    acc2 = fmaf(b6, x6, acc2);
                    acc3 = fmaf(b7, x7, acc3);
                }
            }
            h[(size_t)node * DIM + lane] = (acc0 + acc1) + (acc2 + acc3);
        }
    } else {
        // ---- slow path (cnt > CAP, never for this input) ----
        for (int j = tid; j < SPAN * DIM; j += 1024) {
            int node = b * SPAN + (j >> 6);
            if (node < N) h[(size_t)node * DIM + (j & 63)] = 0.f;
        }
        __syncthreads();
        for (int i = tid; i < cnt; i += 1024) {
            unsigned long long r = pay[bstart + i];
            unsigned s = (unsigned)(r >> 40);
            if (s >= (unsigned)N) s = 0;
            int node = b * SPAN + (int)((r >> 32) & (SPAN - 1));
            if (node < N) {
                float a = tanhf(a_src[s] + a_dst[node]) *
                          __uint_as_float((unsigned)r);
                for (int k = 0; k < DIM; ++k)
                    atomicAdd(&h[(size_t)node * DIM + k],
                              a * x32[(size_t)s * DIM + k]);
            }
        }
    }
}

// ---------------- Fallback (round-1 atomic path, known-good) ---------------
__global__ void zero_h_kernel(float* __restrict__ p, int n) {
    int i = blockIdx.x * blockDim.x + threadIdx.x;
    if (i < n) p[i] = 0.f;
}

__global__ void edge_kernel_atomic(const float* __restrict__ x,
                                   const float* __restrict__ ew,
                                   const int* __restrict__ src_idx,
                                   const int* __restrict__ dst_idx,
                                   const float* __restrict__ a_src,
                                   const float* __restrict__ a_dst,
                                   float* __restrict__ h,
                                   int E) {
    int gid  = blockIdx.x * blockDim.x + threadIdx.x;
    int e    = gid >> 6;
    int lane = threadIdx.x & 63;
    if (e >= E) return;
    int s = src_idx[e];
    int t = dst_idx[e];
    float a  = tanhf(a_src[s] + a_dst[t]) * ew[e];
    float xv = x[(size_t)s * DIM + lane];
    atomicAdd(&h[(size_t)t * DIM + lane], a * xv);
}

__global__ void score_only_kernel(const float* __restrict__ x,
                                  const float* __restrict__ w_src,
                                  const float* __restrict__ w_dst,
                                  float* __restrict__ a_src,
                                  float* __restrict__ a_dst,
                                  int N) {
    int gid  = blockIdx.x * blockDim.x + threadIdx.x;
    int node = gid >> 6;
    int lane = threadIdx.x & 63;
    if (node >= N) return;
    float xv = x[(size_t)node * DIM + lane];
    float s1 = xv * w_src[lane];
    float s2 = xv * w_dst[lane];
    #pragma unroll
    for (int off = 32; off > 0; off >>= 1) {
        s1 += __shfl_down(s1, off, 64);
        s2 += __shfl_down(s2, off, 64);
    }
    if (lane == 0) {
        a_src[node] = s1;
        a_dst[node] = s2;
    }
}

extern "C" void kernel_launch(void* const* d_in, const int* in_sizes, int n_in,
                              void* d_out, int out_size, void* d_ws, size_t ws_size,
                              hipStream_t stream) {
    const float* x     = (const float*)d_in[0];
    const float* w_src = (const float*)d_in[1];
    const float* w_dst = (const float*)d_in[2];
    const float* ew    = (const float*)d_in[3];
    const int*   src   = (const int*)d_in[4];
    const int*   dst   = (const int*)d_in[5];
    float* h = (float*)d_out;

    int N = in_sizes[0] / DIM;
    int E = in_sizes[3];

    int K    = (N + SPAN - 1) / SPAN;     // buckets
    int Ntot = K * NBIN;                  // count-matrix entries
    int NBs  = (Ntot + 511) / 512;        // 512-wide scan blocks

    // ws layout (4B units):
    // [a_src N][a_dst N][moffs Ntot+1][bsum NBs][pad][pay E*8B][xh N*DIM*2B]
    float* a_src  = (float*)d_ws;
    float* a_dst  = a_src + N;
    int*   moffs  = (int*)(a_dst + N);
    int*   bsum   = moffs + Ntot + 1;
    size_t head_bytes = ((size_t)(2 * N) + (size_t)Ntot + 1 + (size_t)NBs) * 4;
    size_t pay_off = (head_bytes + 15) & ~(size_t)15;
    unsigned long long* pay = (unsigned long long*)((char*)d_ws + pay_off);
    size_t xh_off = pay_off + (size_t)E * 8;
    __half* xh = (__half*)((char*)d_ws + xh_off);
    size_t need = xh_off + (size_t)N * DIM * 2;

    int score_blocks = (N + 3) / 4;

    if (ws_size < need || K > KMAX || NBs > 512 || N >= (1 << 24)) {
        // fallback: round-1 atomic path
        score_only_kernel<<<score_blocks, 256, 0, stream>>>(x, w_src, w_dst,
                                                            a_src, a_dst, N);
        int ob = (out_size + 255) / 256;
        zero_h_kernel<<<ob, 256, 0, stream>>>(h, out_size);
        int edge_blocks = (E + 3) / 4;
        edge_kernel_atomic<<<edge_blocks, 256, 0, stream>>>(x, ew, src, dst,
                                                            a_src, a_dst, h, E);
        return;
    }

    score_kernel<<<score_blocks, 256, 0, stream>>>(x, w_src, w_dst,
                                                   a_src, a_dst, xh, N);
    hist_coarse<<<NBIN, 1024, 0, stream>>>(dst, moffs, E, N, K);
    scan_part<<<NBs, 512, 0, stream>>>(moffs, bsum, Ntot);
    scan_top<<<1, 512, 0, stream>>>(bsum, NBs);
    binpass_kernel<<<NBIN, 1024, 0, stream>>>(ew, src, dst, moffs, bsum,
                                              pay, E, N, K);
    sort_gather_kernel<<<K, 1024, 0, stream>>>(xh, x, a_src, a_dst, pay,
                                               moffs, bsum, h, N, K, E);
}

// Round 11
// 188.841 us; speedup vs baseline: 1.0196x; 1.0196x over previous
//
#include <hip/hip_runtime.h>
#include <hip/hip_fp16.h>
#include <math.h>

#define DIM   64
#define SPAN  128           // nodes per bucket
#define SHIFT 7             // log2(SPAN)
#define NBIN  256           // binning blocks
#define KMAX  1024          // max buckets (N <= 131072)
#define CAP   3072          // per-bucket LDS staging (24 KB srec)

// ---------------- Kernel 1: fused score + fp16 copy + coarse hist ----------
// Phase A (node waves): a_src/a_dst + xh.  Phase B (edge stride): LDS hist,
// written as deterministic matrix cnt[bucket*NBIN + block] (no zeroing needed).
__global__ __launch_bounds__(1024) void score_hist_kernel(
        const float* __restrict__ x,
        const float* __restrict__ w_src,
        const float* __restrict__ w_dst,
        float* __restrict__ a_src,
        float* __restrict__ a_dst,
        __half* __restrict__ xh,
        const int* __restrict__ dst,
        int* __restrict__ cnt,
        int N, int E, int K) {
    __shared__ int lh[KMAX];
    int tid = threadIdx.x;
    for (int j = tid; j < K; j += 1024) lh[j] = 0;
    // ---- phase A: scores (doesn't touch lh) ----
    int lane = tid & 63;
    int wv = (blockIdx.x << 4) + (tid >> 6);
    int nw = gridDim.x << 4;
    for (int node = wv; node < N; node += nw) {
        float xv = x[(size_t)node * DIM + lane];
        xh[(size_t)node * DIM + lane] = __float2half_rn(xv);
        float s1 = xv * w_src[lane];
        float s2 = xv * w_dst[lane];
        #pragma unroll
        for (int off = 32; off > 0; off >>= 1) {
            s1 += __shfl_down(s1, off, 64);
            s2 += __shfl_down(s2, off, 64);
        }
        if (lane == 0) {
            a_src[node] = s1;
            a_dst[node] = s2;
        }
    }
    __syncthreads();
    // ---- phase B: histogram ----
    for (int e = blockIdx.x * 1024 + tid; e < E; e += gridDim.x * 1024) {
        unsigned t = (unsigned)dst[e];
        if (t >= (unsigned)N) t = 0;              // guard
        atomicAdd(&lh[t >> SHIFT], 1);
    }
    __syncthreads();
    for (int j = tid; j < K; j += 1024)
        cnt[j * NBIN + blockIdx.x] = lh[j];
}

// ---------------- Kernels 2-3: exclusive scan, 512-wide --------------------
// In-place safe: stages into LDS before any write; block i writes own window.
__global__ __launch_bounds__(512) void scan_part(int* __restrict__ data,
                                                 int* __restrict__ bsum, int n) {
    __shared__ int buf[2][512];
    int tid = threadIdx.x;
    int i = blockIdx.x * 512 + tid;
    int v = (i < n) ? data[i] : 0;
    int sel = 0;
    buf[0][tid] = v;
    __syncthreads();
    for (int off = 1; off < 512; off <<= 1) {
        int nsel = sel ^ 1;
        buf[nsel][tid] = buf[sel][tid] + ((tid >= off) ? buf[sel][tid - off] : 0);
        __syncthreads();
        sel = nsel;
    }
    if (i < n) data[i] = buf[sel][tid] - v;       // exclusive
    if (tid == 511) bsum[blockIdx.x] = buf[sel][511];
}

__global__ __launch_bounds__(512) void scan_top(int* __restrict__ bsum, int NB) {
    __shared__ int buf[2][512];
    int tid = threadIdx.x;
    int v = (tid < NB) ? bsum[tid] : 0;
    int sel = 0;
    buf[0][tid] = v;
    __syncthreads();
    for (int off = 1; off < 512; off <<= 1) {
        int nsel = sel ^ 1;
        buf[nsel][tid] = buf[sel][tid] + ((tid >= off) ? buf[sel][tid - off] : 0);
        __syncthreads();
        sel = nsel;
    }
    if (tid < NB) bsum[tid] = buf[sel][tid] - v;  // exclusive
}

// ---------------- Kernel 4: binpass — partition + attention ----------------
// pay = ((src<<8)|dst_local)<<32 | f32bits(a),  a = tanh(as[s]+ad[t])*ew.
__global__ __launch_bounds__(1024) void binpass_kernel(
        const float* __restrict__ ew,
        const int* __restrict__ src_idx,
        const int* __restrict__ dst_idx,
        const float* __restrict__ a_src,
        const float* __restrict__ a_dst,
        const int* __restrict__ moffs,
        const int* __restrict__ bsum,
        unsigned long long* __restrict__ pay,
        int E, int N, int K) {
    __shared__ int lcur[KMAX];
    int tid = threadIdx.x;
    for (int j = tid; j < K; j += 1024) {
        int i = j * NBIN + blockIdx.x;
        lcur[j] = moffs[i] + bsum[i >> 9];        // scan blocks are 512-wide
    }
    __syncthreads();
    for (int base = blockIdx.x * 1024; base < E; base += NBIN * 1024) {
        int e = base + tid;
        if (e < E) {
            unsigned s = (unsigned)src_idx[e];
            unsigned t = (unsigned)dst_idx[e];
            if (s >= (unsigned)N) s = 0;          // guard
            if (t >= (unsigned)N) t = 0;          // guard
            float a = tanhf(a_src[s] + a_dst[t]) * ew[e];
            int bk = (int)(t >> SHIFT);
            int pos = atomicAdd(&lcur[bk], 1);    // LDS cursor, block-local
            unsigned rec = (s << 8) | (t & (SPAN - 1));
            pay[pos] = ((unsigned long long)rec << 32) |
                       (unsigned long long)__float_as_uint(a);
        }
    }
}

// ---------------- Kernel 5: fused sort + pair-gather -----------------------
// Counting-sort bucket in LDS, then wave-per-node gather where ONE half2
// wave-load serves TWO edges (lanes 0-31 edge j, 32-63 edge j+1):
// 8 loads in flight cover 16 edges -> 2x edges in flight vs scalar gather.
__global__ __launch_bounds__(1024) void sort_gather_kernel(
        const __half* __restrict__ xh,
        const float* __restrict__ x32,
        const unsigned long long* __restrict__ pay,
        const int* __restrict__ moffs,
        const int* __restrict__ bsum,
        float* __restrict__ h,
        int N, int K, int E) {
    __shared__ unsigned long long srec[CAP];      // 24 KB
    __shared__ unsigned short sidx[CAP];          // 6 KB
    __shared__ int hcnt[SPAN];
    __shared__ int hoff[2][SPAN];
    __shared__ int lcur[SPAN];
    __shared__ int nstart[SPAN];
    int tid = threadIdx.x;
    int b   = blockIdx.x;
    int i0 = b * NBIN;
    int bstart = moffs[i0] + bsum[i0 >> 9];
    int bend;
    if (b == K - 1) bend = E;
    else { int i1 = (b + 1) * NBIN; bend = moffs[i1] + bsum[i1 >> 9]; }
    int cnt = bend - bstart;

    if (cnt <= CAP) {
        // ---- stage + per-node histogram ----
        if (tid < SPAN) hcnt[tid] = 0;
        __syncthreads();
        for (int i = tid; i < cnt; i += 1024) {
            unsigned long long r = pay[bstart + i];
            srec[i] = r;
            atomicAdd(&hcnt[(int)((r >> 32) & (SPAN - 1))], 1);
        }
        __syncthreads();
        // ---- inclusive scan of hcnt[SPAN] ----
        int sel = 0;
        if (tid < SPAN) hoff[0][tid] = hcnt[tid];
        __syncthreads();
        for (int off = 1; off < SPAN; off <<= 1) {
            int nsel = sel ^ 1;
            if (tid < SPAN)
                hoff[nsel][tid] = hoff[sel][tid] +
                                  ((tid >= off) ? hoff[sel][tid - off] : 0);
            __syncthreads();
            sel = nsel;
        }
        if (tid < SPAN) {
            int excl = hoff[sel][tid] - hcnt[tid];
            nstart[tid] = excl;
            lcur[tid]   = excl;
        }
        __syncthreads();
        // ---- permute indices only ----
        for (int i = tid; i < cnt; i += 1024) {
            unsigned long long r = srec[i];
            int d = (int)((r >> 32) & (SPAN - 1));
            int pos = atomicAdd(&lcur[d], 1);
            sidx[pos] = (unsigned short)i;
        }
        __syncthreads();
        // ---- pair-gather: wave per node ----
        int lane = tid & 63;
        int wave = tid >> 6;                      // 16 waves
        int half = lane >> 5;                     // 0: even slots, 1: odd
        int hl   = lane & 31;
        const __half2* xh2 = (const __half2*)xh;
        for (int d = wave; d < SPAN; d += 16) {
            int node = b * SPAN + d;
            if (node >= N) break;                 // only last bucket
            int p   = nstart[d];
            int deg = hcnt[d];
            int m   = deg - 1;
            float2 acc0 = {0.f, 0.f}, acc1 = {0.f, 0.f};
            float2 acc2 = {0.f, 0.f}, acc3 = {0.f, 0.f};
            float2 acc4 = {0.f, 0.f}, acc5 = {0.f, 0.f};
            float2 acc6 = {0.f, 0.f}, acc7 = {0.f, 0.f};
            for (int c = 0; c < deg; c += 16) {   // 16 slots, 8 pair-loads
                int j0 = c + 0  + half; int j1 = c + 2  + half;
                int j2 = c + 4  + half; int j3 = c + 6  + half;
                int j4 = c + 8  + half; int j5 = c + 10 + half;
                int j6 = c + 12 + half; int j7 = c + 14 + half;
                unsigned long long r0 = srec[sidx[p + (j0 <= m ? j0 : m)]];
                unsigned long long r1 = srec[sidx[p + (j1 <= m ? j1 : m)]];
                unsigned long long r2 = srec[sidx[p + (j2 <= m ? j2 : m)]];
                unsigned long long r3 = srec[sidx[p + (j3 <= m ? j3 : m)]];
                unsigned long long r4 = srec[sidx[p + (j4 <= m ? j4 : m)]];
                unsigned long long r5 = srec[sidx[p + (j5 <= m ? j5 : m)]];
                unsigned long long r6 = srec[sidx[p + (j6 <= m ? j6 : m)]];
                unsigned long long r7 = srec[sidx[p + (j7 <= m ? j7 : m)]];
                float a0 = (j0 <= m) ? __uint_as_float((unsigned)r0) : 0.f;
                float a1 = (j1 <= m) ? __uint_as_float((unsigned)r1) : 0.f;
                float a2 = (j2 <= m) ? __uint_as_float((unsigned)r2) : 0.f;
                float a3 = (j3 <= m) ? __uint_as_float((unsigned)r3) : 0.f;
                float a4 = (j4 <= m) ? __uint_as_float((unsigned)r4) : 0.f;
                float a5 = (j5 <= m) ? __uint_as_float((unsigned)r5) : 0.f;
                float a6 = (j6 <= m) ? __uint_as_float((unsigned)r6) : 0.f;
                float a7 = (j7 <= m) ? __uint_as_float((unsigned)r7) : 0.f;
                unsigned s0 = (unsigned)(r0 >> 40); if (s0 >= (unsigned)N) s0 = 0;
                unsigned s1 = (unsigned)(r1 >> 40); if (s1 >= (unsigned)N) s1 = 0;
                unsigned s2 = (unsigned)(r2 >> 40); if (s2 >= (unsigned)N) s2 = 0;
                unsigned s3 = (unsigned)(r3 >> 40); if (s3 >= (unsigned)N) s3 = 0;
                unsigned s4 = (unsigned)(r4 >> 40); if (s4 >= (unsigned)N) s4 = 0;
                unsigned s5 = (unsigned)(r5 >> 40); if (s5 >= (unsigned)N) s5 = 0;
                unsigned s6 = (unsigned)(r6 >> 40); if (s6 >= (unsigned)N) s6 = 0;
                unsigned s7 = (unsigned)(r7 >> 40); if (s7 >= (unsigned)N) s7 = 0;
                float2 x0 = __half22float2(xh2[(size_t)s0 * 32 + hl]);
                float2 x1 = __half22float2(xh2[(size_t)s1 * 32 + hl]);
                float2 x2 = __half22float2(xh2[(size_t)s2 * 32 + hl]);
                float2 x3 = __half22float2(xh2[(size_t)s3 * 32 + hl]);
                float2 x4 = __half22float2(xh2[(size_t)s4 * 32 + hl]);
                float2 x5 = __half22float2(xh2[(size_t)s5 * 32 + hl]);
                float2 x6 = __half22float2(xh2[(size_t)s6 * 32 + hl]);
                float2 x7 = __half22float2(xh2[(size_t)s7 * 32 + hl]);
                acc0.x = fmaf(a0, x0.x, acc0.x); acc0.y = fmaf(a0, x0.y, acc0.y);
                acc1.x = fmaf(a1, x1.x, acc1.x); acc1.y = fmaf(a1, x1.y, acc1.y);
                acc2.x = fmaf(a2, x2.x, acc2.x); acc2.y = fmaf(a2, x2.y, acc2.y);
                acc3.x = fmaf(a3, x3.x, acc3.x); acc3.y = fmaf(a3, x3.y, acc3.y);
                acc4.x = fmaf(a4, x4.x, acc4.x); acc4.y = fmaf(a4, x4.y, acc4.y);
                acc5.x = fmaf(a5, x5.x, acc5.x); acc5.y = fmaf(a5, x5.y, acc5.y);
                acc6.x = fmaf(a6, x6.x, acc6.x); acc6.y = fmaf(a6, x6.y, acc6.y);
                acc7.x = fmaf(a7, x7.x, acc7.x); acc7.y = fmaf(a7, x7.y, acc7.y);
            }
            float2 acc;
            acc.x = ((acc0.x + acc1.x) + (acc2.x + acc3.x)) +
                    ((acc4.x + acc5.x) + (acc6.x + acc7.x));
            acc.y = ((acc0.y + acc1.y) + (acc2.y + acc3.y)) +
                    ((acc4.y + acc5.y) + (acc6.y + acc7.y));
            acc.x += __shfl_xor(acc.x, 32, 64);   // even-slot + odd-slot halves
            acc.y += __shfl_xor(acc.y, 32, 64);
            if (half == 0)
                ((float2*)h)[(size_t)node * 32 + hl] = acc;   // deg-0 -> 0
        }
    } else {
        // ---- slow path (cnt > CAP, never for this input) ----
        for (int j = tid; j < SPAN * DIM; j += 1024) {
            int node = b * SPAN + (j >> 6);
            if (node < N) h[(size_t)node * DIM + (j & 63)] = 0.f;
        }
        __syncthreads();
        for (int i = tid; i < cnt; i += 1024) {
            unsigned long long r = pay[bstart + i];
            unsigned s = (unsigned)(r >> 40);
            if (s >= (unsigned)N) s = 0;
            int node = b * SPAN + (int)((r >> 32) & (SPAN - 1));
            float a = __uint_as_float((unsigned)r);
            if (node < N)
                for (int k = 0; k < DIM; ++k)
                    atomicAdd(&h[(size_t)node * DIM + k],
                              a * x32[(size_t)s * DIM + k]);
        }
    }
}

// ---------------- Fallback (round-1 atomic path, known-good) ---------------
__global__ void zero_h_kernel(float* __restrict__ p, int n) {
    int i = blockIdx.x * blockDim.x + threadIdx.x;
    if (i < n) p[i] = 0.f;
}

__global__ void edge_kernel_atomic(const float* __restrict__ x,
                                   const float* __restrict__ ew,
                                   const int* __restrict__ src_idx,
                                   const int* __restrict__ dst_idx,
                                   const float* __restrict__ a_src,
                                   const float* __restrict__ a_dst,
                                   float* __restrict__ h,
                                   int E) {
    int gid  = blockIdx.x * blockDim.x + threadIdx.x;
    int e    = gid >> 6;
    int lane = threadIdx.x & 63;
    if (e >= E) return;
    int s = src_idx[e];
    int t = dst_idx[e];
    float a  = tanhf(a_src[s] + a_dst[t]) * ew[e];
    float xv = x[(size_t)s * DIM + lane];
    atomicAdd(&h[(size_t)t * DIM + lane], a * xv);
}

__global__ void score_only_kernel(const float* __restrict__ x,
                                  const float* __restrict__ w_src,
                                  const float* __restrict__ w_dst,
                                  float* __restrict__ a_src,
                                  float* __restrict__ a_dst,
                                  int N) {
    int gid  = blockIdx.x * blockDim.x + threadIdx.x;
    int node = gid >> 6;
    int lane = threadIdx.x & 63;
    if (node >= N) return;
    float xv = x[(size_t)node * DIM + lane];
    float s1 = xv * w_src[lane];
    float s2 = xv * w_dst[lane];
    #pragma unroll
    for (int off = 32; off > 0; off >>= 1) {
        s1 += __shfl_down(s1, off, 64);
        s2 += __shfl_down(s2, off, 64);
    }
    if (lane == 0) {
        a_src[node] = s1;
        a_dst[node] = s2;
    }
}

extern "C" void kernel_launch(void* const* d_in, const int* in_sizes, int n_in,
                              void* d_out, int out_size, void* d_ws, size_t ws_size,
                              hipStream_t stream) {
    const float* x     = (const float*)d_in[0];
    const float* w_src = (const float*)d_in[1];
    const float* w_dst = (const float*)d_in[2];
    const float* ew    = (const float*)d_in[3];
    const int*   src   = (const int*)d_in[4];
    const int*   dst   = (const int*)d_in[5];
    float* h = (float*)d_out;

    int N = in_sizes[0] / DIM;
    int E = in_sizes[3];

    int K    = (N + SPAN - 1) / SPAN;     // buckets
    int Ntot = K * NBIN;                  // count-matrix entries
    int NBs  = (Ntot + 511) / 512;        // 512-wide scan blocks

    // ws layout (4B units):
    // [a_src N][a_dst N][moffs Ntot+1][bsum NBs][pad][pay E*8B][xh N*DIM*2B]
    float* a_src  = (float*)d_ws;
    float* a_dst  = a_src + N;
    int*   moffs  = (int*)(a_dst + N);
    int*   bsum   = moffs + Ntot + 1;
    size_t head_bytes = ((size_t)(2 * N) + (size_t)Ntot + 1 + (size_t)NBs) * 4;
    size_t pay_off = (head_bytes + 15) & ~(size_t)15;
    unsigned long long* pay = (unsigned long long*)((char*)d_ws + pay_off);
    size_t xh_off = pay_off + (size_t)E * 8;
    __half* xh = (__half*)((char*)d_ws + xh_off);
    size_t need = xh_off + (size_t)N * DIM * 2;

    if (ws_size < need || K > KMAX || NBs > 512 || N >= (1 << 24)) {
        // fallback: round-1 atomic path
        int score_blocks = (N + 3) / 4;
        score_only_kernel<<<score_blocks, 256, 0, stream>>>(x, w_src, w_dst,
                                                            a_src, a_dst, N);
        int ob = (out_size + 255) / 256;
        zero_h_kernel<<<ob, 256, 0, stream>>>(h, out_size);
        int edge_blocks = (E + 3) / 4;
        edge_kernel_atomic<<<edge_blocks, 256, 0, stream>>>(x, ew, src, dst,
                                                            a_src, a_dst, h, E);
        return;
    }

    score_hist_kernel<<<NBIN, 1024, 0, stream>>>(x, w_src, w_dst, a_src, a_dst,
                                                 xh, dst, moffs, N, E, K);
    scan_part<<<NBs, 512, 0, stream>>>(moffs, bsum, Ntot);
    scan_top<<<1, 512, 0, stream>>>(bsum, NBs);
    binpass_kernel<<<NBIN, 1024, 0, stream>>>(ew, src, dst, a_src, a_dst,
                                              moffs, bsum, pay, E, N, K);
    sort_gather_kernel<<<K, 1024, 0, stream>>>(xh, x, pay, moffs, bsum,
                                               h, N, K, E);
}